// Round 5
// baseline (748.053 us; speedup 1.0000x reference)
//
#include <hip/hip_runtime.h>
#include <math.h>

// ---------------------------------------------------------------------------
// DQNNet GNN, f16x3 split-precision MFMA GEMMs (error ~2^-22, fp32-equivalent).
//   h = l2norm(relu(x @ W1^T + b1))            [gemm_l1, + fused edge histogram]
//   2x: z = h @ [W2;W3]^T                      [gemm_z, first fused with CSR fill]
//       h = l2norm(relu([z1+b2 | segsum(z2[src])+b3]))   [fin]
//   out = relu(h @ Wd1^T + bd1) @ Wd2^T + bd2  [gemm_head, matvec fused]
// h stored as (hi,lo) f16 pairs packed in u32 (same bytes as fp32).
// GEMM: 512 threads = 8 waves (2 row-halves x 4 col-quarters), 64x64/wave,
// 64 acc VGPRs/wave -> 4 waves/SIMD, 2 blocks/CU (16 waves/CU).
// ---------------------------------------------------------------------------

typedef _Float16 f16x8 __attribute__((ext_vector_type(8)));
typedef float    f32x16 __attribute__((ext_vector_type(16)));

constexpr int DIM = 256;
constexpr int BM  = 128;
constexpr int BK  = 32;    // K-slice per staged tile
constexpr int SA  = 40;    // padded LDS row stride (f16)

__device__ __forceinline__ unsigned pk_hi2(float a, float b) {
    unsigned short ha = __builtin_bit_cast(unsigned short, (_Float16)a);
    unsigned short hb = __builtin_bit_cast(unsigned short, (_Float16)b);
    return (unsigned)ha | ((unsigned)hb << 16);
}
__device__ __forceinline__ unsigned pk_lo2(float a, float b) {
    _Float16 ha = (_Float16)a, hb = (_Float16)b;
    unsigned short la = __builtin_bit_cast(unsigned short, (_Float16)(a - (float)ha));
    unsigned short lb = __builtin_bit_cast(unsigned short, (_Float16)(b - (float)hb));
    return (unsigned)la | ((unsigned)lb << 16);
}
__device__ __forceinline__ unsigned pack_pair(float v) {
    _Float16 hi = (_Float16)v;
    _Float16 lo = (_Float16)(v - (float)hi);
    return (unsigned)__builtin_bit_cast(unsigned short, hi)
         | ((unsigned)__builtin_bit_cast(unsigned short, lo) << 16);
}

// AMODE: 0 = A is fp32 (split during staging); 1 = A is (hi,lo)-pair u32.
// EPI:   0 = raw fp32 z; 1 = bias+relu+l2norm -> pair; 2 = bias+relu+matvec.
template <int AMODE, int EPI>
__device__ __forceinline__
void gemm_body(const void* __restrict__ Av,
               const float* __restrict__ WA, const float* __restrict__ WB,
               const float* __restrict__ bA, const float* __restrict__ bB,
               void* __restrict__ outv,
               const float* __restrict__ wd2, const float* __restrict__ bd2,
               float* __restrict__ out1, int M)
{
    // LDS: As_hi[128][40] As_lo[128][40] Ws_hi[256][40] Ws_lo[256][40] = 60 KB
    __shared__ __align__(16) _Float16 smem[30720];
    _Float16* As_hi = smem;
    _Float16* As_lo = smem + 5120;
    _Float16* Ws_hi = smem + 10240;
    _Float16* Ws_lo = smem + 20480;

    const int tid = threadIdx.x;
    const int l31 = tid & 31;
    const int lh  = (tid >> 5) & 1;
    const int w   = tid >> 6;          // wave 0..7
    const int wr  = w >> 2;            // row half: rows wr*64..+64
    const int wc  = w & 3;             // col quarter: cols wc*64..+64
    const int bm0 = blockIdx.x * BM;

    const unsigned* Au = (const unsigned*)Av;
    const int srow = tid >> 2;         // A staging: row 0..127
    const int sch  = (tid & 3) * 8;    // A staging: k-chunk of 8
    const int srw  = tid >> 1;         // W staging: row 0..255
    const int scw  = (tid & 1) * 16;   // W staging: k-chunk of 16

    uint4 pa[2];
    auto fetchA = [&](int t) {
        const int k0 = t * BK;
        const int gr = bm0 + srow;
        if (gr < M) {
            pa[0] = *(const uint4*)&Au[(size_t)gr * 256 + k0 + sch];
            pa[1] = *(const uint4*)&Au[(size_t)gr * 256 + k0 + sch + 4];
        } else {
            pa[0] = uint4{0u,0u,0u,0u}; pa[1] = uint4{0u,0u,0u,0u};
        }
    };
    auto stageA = [&]() {
        uint4 hi, lo;
        if (AMODE == 0) {
            const float x0 = __builtin_bit_cast(float, pa[0].x);
            const float x1 = __builtin_bit_cast(float, pa[0].y);
            const float x2 = __builtin_bit_cast(float, pa[0].z);
            const float x3 = __builtin_bit_cast(float, pa[0].w);
            const float x4 = __builtin_bit_cast(float, pa[1].x);
            const float x5 = __builtin_bit_cast(float, pa[1].y);
            const float x6 = __builtin_bit_cast(float, pa[1].z);
            const float x7 = __builtin_bit_cast(float, pa[1].w);
            hi = uint4{pk_hi2(x0,x1), pk_hi2(x2,x3), pk_hi2(x4,x5), pk_hi2(x6,x7)};
            lo = uint4{pk_lo2(x0,x1), pk_lo2(x2,x3), pk_lo2(x4,x5), pk_lo2(x6,x7)};
        } else {
            hi = uint4{__builtin_amdgcn_perm(pa[0].y, pa[0].x, 0x05040100u),
                       __builtin_amdgcn_perm(pa[0].w, pa[0].z, 0x05040100u),
                       __builtin_amdgcn_perm(pa[1].y, pa[1].x, 0x05040100u),
                       __builtin_amdgcn_perm(pa[1].w, pa[1].z, 0x05040100u)};
            lo = uint4{__builtin_amdgcn_perm(pa[0].y, pa[0].x, 0x07060302u),
                       __builtin_amdgcn_perm(pa[0].w, pa[0].z, 0x07060302u),
                       __builtin_amdgcn_perm(pa[1].y, pa[1].x, 0x07060302u),
                       __builtin_amdgcn_perm(pa[1].w, pa[1].z, 0x07060302u)};
        }
        *(uint4*)&As_hi[srow * SA + sch] = hi;
        *(uint4*)&As_lo[srow * SA + sch] = lo;
    };
    auto stageW = [&](int t) {   // fetch+stage in-loop: W is L2-resident, short latency
        const int k0 = t * BK;
        const float* src = (srw < 128) ? &WA[(size_t)srw * 256]
                                       : &WB[(size_t)(srw - 128) * 256];
        const float4 w0 = *(const float4*)&src[k0 + scw];
        const float4 w1 = *(const float4*)&src[k0 + scw + 4];
        const float4 w2 = *(const float4*)&src[k0 + scw + 8];
        const float4 w3 = *(const float4*)&src[k0 + scw + 12];
        uint4 hi0{pk_hi2(w0.x,w0.y), pk_hi2(w0.z,w0.w), pk_hi2(w1.x,w1.y), pk_hi2(w1.z,w1.w)};
        uint4 hi1{pk_hi2(w2.x,w2.y), pk_hi2(w2.z,w2.w), pk_hi2(w3.x,w3.y), pk_hi2(w3.z,w3.w)};
        uint4 lo0{pk_lo2(w0.x,w0.y), pk_lo2(w0.z,w0.w), pk_lo2(w1.x,w1.y), pk_lo2(w1.z,w1.w)};
        uint4 lo1{pk_lo2(w2.x,w2.y), pk_lo2(w2.z,w2.w), pk_lo2(w3.x,w3.y), pk_lo2(w3.z,w3.w)};
        *(uint4*)&Ws_hi[srw * SA + scw]     = hi0;
        *(uint4*)&Ws_hi[srw * SA + scw + 8] = hi1;
        *(uint4*)&Ws_lo[srw * SA + scw]     = lo0;
        *(uint4*)&Ws_lo[srw * SA + scw + 8] = lo1;
    };

    f32x16 acc[2][2];
    #pragma unroll
    for (int tr = 0; tr < 2; ++tr)
        #pragma unroll
        for (int tc = 0; tc < 2; ++tc)
            #pragma unroll
            for (int i = 0; i < 16; ++i) acc[tr][tc][i] = 0.0f;

    fetchA(0);

    #pragma unroll 1
    for (int t = 0; t < DIM / BK; ++t) {
        stageA();
        stageW(t);
        __syncthreads();
        if (t < DIM / BK - 1) fetchA(t + 1);

        #pragma unroll
        for (int ks = 0; ks < 2; ++ks) {
            f16x8 ah[2], al[2], wh[2], wl[2];
            #pragma unroll
            for (int tr = 0; tr < 2; ++tr) {
                const int off = (wr * 64 + tr * 32 + l31) * SA + ks * 16 + lh * 8;
                ah[tr] = *(const f16x8*)&As_hi[off];
                al[tr] = *(const f16x8*)&As_lo[off];
            }
            #pragma unroll
            for (int tc = 0; tc < 2; ++tc) {
                const int off = (wc * 64 + tc * 32 + l31) * SA + ks * 16 + lh * 8;
                wh[tc] = *(const f16x8*)&Ws_hi[off];
                wl[tc] = *(const f16x8*)&Ws_lo[off];
            }
            #pragma unroll
            for (int tr = 0; tr < 2; ++tr)
                #pragma unroll
                for (int tc = 0; tc < 2; ++tc) {
                    acc[tr][tc] = __builtin_amdgcn_mfma_f32_32x32x16_f16(ah[tr], wh[tc], acc[tr][tc], 0, 0, 0);
                    acc[tr][tc] = __builtin_amdgcn_mfma_f32_32x32x16_f16(ah[tr], wl[tc], acc[tr][tc], 0, 0, 0);
                    acc[tr][tc] = __builtin_amdgcn_mfma_f32_32x32x16_f16(al[tr], wh[tc], acc[tr][tc], 0, 0, 0);
                }
        }
        __syncthreads();
    }

    // C/D layout (32x32): col = lane&31, row = (reg&3) + 8*(reg>>2) + 4*(lane>>5)

    if (EPI == 0) {
        float* z = (float*)outv;
        #pragma unroll
        for (int tr = 0; tr < 2; ++tr)
            #pragma unroll
            for (int i = 0; i < 16; ++i) {
                const int r  = wr * 64 + tr * 32 + 4 * lh + (i & 3) + 8 * (i >> 2);
                const int gr = bm0 + r;
                if (gr < M) {
                    #pragma unroll
                    for (int tc = 0; tc < 2; ++tc)
                        z[(size_t)gr * 256 + wc * 64 + tc * 32 + l31] = acc[tr][tc][i];
                }
            }
        return;
    }

    {   // bias + relu
        float bias[2];
        #pragma unroll
        for (int tc = 0; tc < 2; ++tc) {
            const int col = wc * 64 + tc * 32 + l31;
            bias[tc] = (col < 128) ? bA[col] : bB[col - 128];
        }
        #pragma unroll
        for (int tr = 0; tr < 2; ++tr)
            #pragma unroll
            for (int tc = 0; tc < 2; ++tc)
                #pragma unroll
                for (int i = 0; i < 16; ++i)
                    acc[tr][tc][i] = fmaxf(acc[tr][tc][i] + bias[tc], 0.0f);
    }

    float* red = (float*)smem;   // [128 rows][4 wc] partials, reused after barrier

    if (EPI == 1) {
        #pragma unroll
        for (int tr = 0; tr < 2; ++tr)
            #pragma unroll
            for (int i = 0; i < 16; ++i) {
                float s = acc[tr][0][i] * acc[tr][0][i] + acc[tr][1][i] * acc[tr][1][i];
                #pragma unroll
                for (int m = 1; m < 32; m <<= 1) s += __shfl_xor(s, m);
                // all 32 lanes (per lh) now hold s; lane tr*16+i publishes it
                if (l31 == tr * 16 + i) {
                    const int r = wr * 64 + tr * 32 + 4 * lh + (i & 3) + 8 * (i >> 2);
                    red[r * 4 + wc] = s;
                }
            }
        __syncthreads();

        unsigned* hp = (unsigned*)outv;
        #pragma unroll
        for (int tr = 0; tr < 2; ++tr)
            #pragma unroll
            for (int i = 0; i < 16; ++i) {
                const int rl = wr * 64 + tr * 32 + 4 * lh + (i & 3) + 8 * (i >> 2);
                const float inv = 1.0f / sqrtf(red[rl * 4] + red[rl * 4 + 1] +
                                               red[rl * 4 + 2] + red[rl * 4 + 3]);
                const int gr = bm0 + rl;
                if (gr < M) {
                    #pragma unroll
                    for (int tc = 0; tc < 2; ++tc)
                        hp[(size_t)gr * 256 + wc * 64 + tc * 32 + l31] =
                            pack_pair(acc[tr][tc][i] * inv);
                }
            }
        return;
    }

    // EPI == 2: fused head matvec
    {
        float wv[2];
        #pragma unroll
        for (int tc = 0; tc < 2; ++tc) wv[tc] = wd2[wc * 64 + tc * 32 + l31];
        #pragma unroll
        for (int tr = 0; tr < 2; ++tr)
            #pragma unroll
            for (int i = 0; i < 16; ++i) {
                float s = acc[tr][0][i] * wv[0] + acc[tr][1][i] * wv[1];
                #pragma unroll
                for (int m = 1; m < 32; m <<= 1) s += __shfl_xor(s, m);
                if (l31 == tr * 16 + i) {
                    const int r = wr * 64 + tr * 32 + 4 * lh + (i & 3) + 8 * (i >> 2);
                    red[r * 4 + wc] = s;
                }
            }
        __syncthreads();
        if (tid < 128) {
            const int gr = bm0 + tid;
            if (gr < M)
                out1[gr] = red[tid * 4] + red[tid * 4 + 1] + red[tid * 4 + 2] +
                           red[tid * 4 + 3] + bd2[0];
        }
    }
}

// ---- layer-1 GEMM with fused edge histogram (extra blocks past gb) ----
__global__ __launch_bounds__(512, 4)
void gemm_l1(const void* __restrict__ Av,
             const float* __restrict__ WA, const float* __restrict__ WB,
             const float* __restrict__ bA, const float* __restrict__ bB,
             void* __restrict__ outv, int M, int gb,
             const int* __restrict__ ei, int E, int* __restrict__ cnt)
{
    if ((int)blockIdx.x < gb) {
        gemm_body<0, 1>(Av, WA, WB, bA, bB, outv, nullptr, nullptr, nullptr, M);
    } else {
        const int base = ((int)blockIdx.x - gb) * 2048 + threadIdx.x;
        #pragma unroll
        for (int k = 0; k < 4; ++k) {
            const int e = base + k * 512;
            if (e < E) atomicAdd(&cnt[ei[E + e]], 1);
        }
    }
}

// ---- z GEMM; first instance fuses the CSR fill (extra blocks past gb) ----
template <int DO_FILL>
__global__ __launch_bounds__(512, 4)
void gemm_z(const void* __restrict__ Av,
            const float* __restrict__ WA, const float* __restrict__ WB,
            void* __restrict__ outv, int M, int gb,
            const int* __restrict__ ei, int E,
            int* __restrict__ cursor, int* __restrict__ esrc)
{
    if ((int)blockIdx.x < gb) {
        gemm_body<1, 0>(Av, WA, WB, nullptr, nullptr, outv, nullptr, nullptr, nullptr, M);
    } else if (DO_FILL) {
        const int base = ((int)blockIdx.x - gb) * 2048 + threadIdx.x;
        #pragma unroll
        for (int k = 0; k < 4; ++k) {
            const int e = base + k * 512;
            if (e < E) {
                int d = ei[E + e];
                int p = atomicAdd(&cursor[d], 1);
                esrc[p] = ei[e];
            }
        }
    }
}

__global__ __launch_bounds__(512, 4)
void gemm_head(const void* __restrict__ Av,
               const float* __restrict__ WA, const float* __restrict__ WB,
               const float* __restrict__ bA, const float* __restrict__ bB,
               const float* __restrict__ wd2, const float* __restrict__ bd2,
               float* __restrict__ out1, int M)
{
    gemm_body<1, 2>(Av, WA, WB, bA, bB, nullptr, wd2, bd2, out1, M);
}

// ------------------------- scans -------------------------

__global__ void scan1_kernel(const int* __restrict__ cnt, int n,
                             int* __restrict__ rp, int* __restrict__ sums)
{
    __shared__ int sm[1024];
    const int tid = threadIdx.x;
    const int i = blockIdx.x * 1024 + tid;
    const int v = (i < n) ? cnt[i] : 0;
    sm[tid] = v;
    __syncthreads();
    for (int off = 1; off < 1024; off <<= 1) {
        int t = (tid >= off) ? sm[tid - off] : 0;
        __syncthreads();
        sm[tid] += t;
        __syncthreads();
    }
    if (i < n) rp[i] = sm[tid] - v;
    if (tid == 1023) sums[blockIdx.x] = sm[tid];
}

__global__ void scan2_kernel(int* __restrict__ sums, int n)
{
    __shared__ int sm[128];
    const int tid = threadIdx.x;
    const int v = (tid < n) ? sums[tid] : 0;
    sm[tid] = v;
    __syncthreads();
    for (int off = 1; off < 128; off <<= 1) {
        int t = (tid >= off) ? sm[tid - off] : 0;
        __syncthreads();
        sm[tid] += t;
        __syncthreads();
    }
    if (tid < n) sums[tid] = sm[tid] - v;
}

__global__ void scan3_kernel(int* __restrict__ rp, const int* __restrict__ sums,
                             int* __restrict__ cursor, int n, int E)
{
    int i = blockIdx.x * blockDim.x + threadIdx.x;
    if (i < n) {
        int v = rp[i] + sums[i >> 10];
        rp[i] = v;
        cursor[i] = v;
    }
    if (i == 0) rp[n] = E;
}

// ---- finalize: h[v] = l2norm(relu([z1[v]+b2 | segsum(z2[src])+b3])) ----
// One wave per node; indices preloaded 64-wide, broadcast via readlane so the
// gather address comes from the scalar unit; 4 accumulators keep 4 gathers live.
__global__ __launch_bounds__(256)
void fin_kernel(const float* __restrict__ z, const int* __restrict__ rp,
                const int* __restrict__ esrc,
                const float* __restrict__ b2, const float* __restrict__ b3,
                unsigned* __restrict__ hp, int M)
{
    const int v    = blockIdx.x * 4 + (threadIdx.x >> 6);
    const int lane = threadIdx.x & 63;
    if (v >= M) return;
    const int beg = rp[v], end = rp[v + 1];
    const int deg = end - beg;

    const float2 z1 = *(const float2*)&z[(size_t)v * DIM + lane * 2];
    const float2 c2 = *(const float2*)&b2[lane * 2];
    const float2 c3 = *(const float2*)&b3[lane * 2];

    const float* z2 = z + 128;
    float ax0 = 0.f, ay0 = 0.f, ax1 = 0.f, ay1 = 0.f;
    float ax2 = 0.f, ay2 = 0.f, ax3 = 0.f, ay3 = 0.f;

    for (int base = 0; base < deg; base += 64) {
        const int cnt = min(64, deg - base);
        int myidx = 0;
        if (lane < cnt) myidx = esrc[beg + base + lane];
        int j = 0;
        for (; j + 3 < cnt; j += 4) {
            const int s0 = __builtin_amdgcn_readlane(myidx, j);
            const int s1 = __builtin_amdgcn_readlane(myidx, j + 1);
            const int s2 = __builtin_amdgcn_readlane(myidx, j + 2);
            const int s3 = __builtin_amdgcn_readlane(myidx, j + 3);
            const float2 g0 = *(const float2*)&z2[(size_t)s0 * DIM + lane * 2];
            const float2 g1 = *(const float2*)&z2[(size_t)s1 * DIM + lane * 2];
            const float2 g2 = *(const float2*)&z2[(size_t)s2 * DIM + lane * 2];
            const float2 g3 = *(const float2*)&z2[(size_t)s3 * DIM + lane * 2];
            ax0 += g0.x; ay0 += g0.y;
            ax1 += g1.x; ay1 += g1.y;
            ax2 += g2.x; ay2 += g2.y;
            ax3 += g3.x; ay3 += g3.y;
        }
        for (; j < cnt; ++j) {
            const int s0 = __builtin_amdgcn_readlane(myidx, j);
            const float2 g0 = *(const float2*)&z2[(size_t)s0 * DIM + lane * 2];
            ax0 += g0.x; ay0 += g0.y;
        }
    }
    const float sx = (ax0 + ax1) + (ax2 + ax3);
    const float sy = (ay0 + ay1) + (ay2 + ay3);

    const float u1x = fmaxf(z1.x + c2.x, 0.f), u1y = fmaxf(z1.y + c2.y, 0.f);
    const float u2x = fmaxf(sx + c3.x, 0.f),  u2y = fmaxf(sy + c3.y, 0.f);

    float ss = u1x * u1x + u1y * u1y + u2x * u2x + u2y * u2y;
    #pragma unroll
    for (int off = 32; off > 0; off >>= 1) ss += __shfl_xor(ss, off);
    const float inv = 1.0f / sqrtf(ss);

    uint2 p1; p1.x = pack_pair(u1x * inv); p1.y = pack_pair(u1y * inv);
    uint2 p2; p2.x = pack_pair(u2x * inv); p2.y = pack_pair(u2y * inv);
    *(uint2*)&hp[(size_t)v * DIM + lane * 2]       = p1;
    *(uint2*)&hp[(size_t)v * DIM + 128 + lane * 2] = p2;
}

// ------------------------- launch -------------------------

extern "C" void kernel_launch(void* const* d_in, const int* in_sizes, int n_in,
                              void* d_out, int out_size, void* d_ws, size_t ws_size,
                              hipStream_t stream)
{
    const float* x   = (const float*)d_in[0];
    const int*   ei  = (const int*)d_in[1];
    const float* W1  = (const float*)d_in[2];
    const float* b1  = (const float*)d_in[3];
    const float* W2  = (const float*)d_in[4];
    const float* b2  = (const float*)d_in[5];
    const float* W3  = (const float*)d_in[6];
    const float* b3  = (const float*)d_in[7];
    const float* Wd1 = (const float*)d_in[8];
    const float* bd1 = (const float*)d_in[9];
    const float* Wd2 = (const float*)d_in[10];
    const float* bd2 = (const float*)d_in[11];
    float* out = (float*)d_out;

    const int M = in_sizes[0] / DIM;   // 100000
    const int E = in_sizes[1] / 2;     // 1600000

    unsigned* hp  = (unsigned*)d_ws;                  // M*256 u32 (hi,lo) pairs
    float*    z   = (float*)(hp + (size_t)M * DIM);   // M*256 f32
    int*   rp     = (int*)(z + (size_t)M * DIM);      // M+1
    int*   cursor = rp + (M + 1);                     // M
    int*   esrc   = cursor + M;                       // E
    int*   sums   = esrc + E;                         // <=128

    hipMemsetAsync(cursor, 0, sizeof(int) * M, stream);

    const int gb  = (M + BM - 1) / BM;       // 782 gemm blocks
    const int hb  = (E + 2047) / 2048;       // edge blocks (4 edges/thread, 512 thr)
    const int nb1 = (M + 1023) / 1024;
    const int fb  = (M + 3) / 4;             // fin: 4 nodes (waves) per block

    // layer 1 GEMM + edge histogram (overlapped in one grid)
    gemm_l1<<<gb + hb, 512, 0, stream>>>(
        x, W1, W1 + 128 * DIM, b1, b1 + 128, hp, M, gb, ei, E, cursor);

    // prefix-sum -> rp, reset cursor to offsets
    scan1_kernel<<<nb1, 1024, 0, stream>>>(cursor, M, rp, sums);
    scan2_kernel<<<1, 128, 0, stream>>>(sums, nb1);
    scan3_kernel<<<(M + 255) / 256, 256, 0, stream>>>(rp, sums, cursor, M, E);

    // z GEMM #1 + CSR fill (overlapped), then finalize
    gemm_z<1><<<gb + hb, 512, 0, stream>>>(hp, W2, W3, z, M, gb, ei, E, cursor, esrc);
    fin_kernel<<<fb, 256, 0, stream>>>(z, rp, esrc, b2, b3, hp, M);

    // z GEMM #2, finalize
    gemm_z<0><<<gb, 512, 0, stream>>>(hp, W2, W3, z, M, gb, nullptr, 0, nullptr, nullptr);
    fin_kernel<<<fb, 256, 0, stream>>>(z, rp, esrc, b2, b3, hp, M);

    // head: out = relu(h @ Wd1^T + bd1) @ Wd2^T + bd2
    gemm_head<<<gb, 512, 0, stream>>>(
        hp, Wd1, Wd1 + 128 * DIM, bd1, bd1 + 128, Wd2, bd2, out, M);
}